// Round 6
// baseline (4368.397 us; speedup 1.0000x reference)
//
#include <hip/hip_runtime.h>
#include <stdint.h>

#define BATCH   4
#define NPTS    16384
#define NPOINT  1024
#define KNN     20
#define KSEL    21   // K+1, includes self

typedef unsigned long long u64;

// ---------------------------------------------------------------------------
// r24: ZERO long-lived register state in FPS. Session facts: allocator
// granted 92/52/84/64/48 VGPRs across five designs (r18-r23) and spilled
// persistent per-thread state EVERY time (FETCH ~415MB / WRITE 80MB
// scratch tracers; 2.3-3.1us/iter). No source-level lever raises the
// grant. Therefore: ALL persistent state lives in LDS; registers hold
// only transient values.
//   - md[16384] in LDS, strided [i][t] (lane-consecutive -> conflict-free
//     b32): 64KB. 16 ds_read + 16 ds_write per thread/iter, thread-owned.
//   - coords: strides 0..5 in LDS via r23's proven pair-packing (float4
//     xy|xy + float2 z|z, conflict-free): 72KB. Strides 6..15 streamed
//     from global (L2-resident, 30 transient loads/thread issued at iter
//     top, hidden under the LDS-stride scan; opaque base blocks LICM).
//   - 1024 thr/block (16 waves): 2x latency hiding vs r22's failed
//     stream. idx = i*1024+t remap is argmax/tie-break-invariant (r20).
// LDS: 49152(xy) + 24576(z) + 65536(md) = 139264B dyn + 256B static.
// FP expression trees byte-identical to validated r16/r19/r23.
// knn_kernel unchanged from validated r19.
// ---------------------------------------------------------------------------
#define FPST        1024                  // FPS threads (16 waves)
#define NSTR        16                    // points per thread, strided
#define LDS_PAIRS   3                     // coord pairs in LDS
#define LDS_STR     (2 * LDS_PAIRS)       // strides 0..5 in LDS
#define STREAM_STR  (NSTR - LDS_STR)      // strides 6..15 streamed
#define DYN_LDS_BYTES ((LDS_PAIRS * FPST * 6 + NSTR * FPST) * 4)  // 139264
#define KNNT 512

// ===========================================================================
// Dispatch 1: FPS producer. One block per batch. 1024 thr.
// ===========================================================================
__global__ __launch_bounds__(FPST)
void fps_kernel(const float* __restrict__ pts, float* __restrict__ out,
                int* __restrict__ slots) {
  const int b = blockIdx.x;
  const float* P = pts + (size_t)b * NPTS * 3;
  float* out_ind = out;                   // [B,NPOINT] (indices as float)
  float* out_q   = out + BATCH * NPOINT;  // [B,NPOINT,3]
  const int t = threadIdx.x;

  extern __shared__ float lds[];
  float4* sxy2 = (float4*)lds;                          // 12288 floats
  float2* sz2  = (float2*)(lds + LDS_PAIRS * FPST * 4); //  6144 floats
  float*  mdl  = lds + LDS_PAIRS * FPST * 6;            // 16384 floats

  // One-time coord fill: pair strides (2u, 2u+1). Same bit values as global.
#pragma unroll
  for (int u = 0; u < LDS_PAIRS; ++u) {
    int ia = (2 * u) * FPST + t;
    int ib = ia + FPST;
    float4 c;
    c.x = P[ia * 3 + 0]; c.y = P[ia * 3 + 1];
    c.z = P[ib * 3 + 0]; c.w = P[ib * 3 + 1];
    sxy2[u * FPST + t] = c;
    float2 zz;
    zz.x = P[ia * 3 + 2]; zz.y = P[ib * 3 + 2];
    sz2[u * FPST + t] = zz;
  }
  // md init: strided [i][t] layout, thread-owned column.
#pragma unroll
  for (int i = 0; i < NSTR; ++i) mdl[i * FPST + t] = 1e10f;

  __shared__ float s_val[2][FPST / 64];
  __shared__ int   s_idx[2][FPST / 64];

  if (t == 0) {
    out_ind[b * NPOINT] = 0.0f;
    slots[b * NPOINT] = 0;
    float ax = P[0], ay = P[1], az = P[2];
    size_t o0 = (size_t)(b * NPOINT) * 3;
    out_q[o0 + 0] = ax; out_q[o0 + 1] = ay; out_q[o0 + 2] = az;
  }
  float qx = P[0], qy = P[1], qz = P[2];

  __syncthreads();   // LDS fill visible

  for (int it = 1; it < NPOINT; ++it) {
    const int p = it & 1;

    // Issue the 30 streamed loads FIRST (transient regs; latency hides
    // under the LDS-stride scan). Opaque base blocks LICM hoisting.
    const float* Pv = P;
    __asm__ volatile("" : "+v"(Pv));
    float gx[STREAM_STR], gy[STREAM_STR], gz[STREAM_STR];
#pragma unroll
    for (int u = 0; u < STREAM_STR; ++u) {
      int idx = (LDS_STR + u) * FPST + t;
      gx[u] = Pv[idx * 3 + 0];
      gy[u] = Pv[idx * 3 + 1];
      gz[u] = Pv[idx * 3 + 2];
    }

    float best = -1.0f;
    int bi = 0;

    // LDS strides 0..5, ascending (bitwise-identical expression tree).
#pragma unroll
    for (int u = 0; u < LDS_PAIRS; ++u) {
      float4 c  = sxy2[u * FPST + t];
      float2 zz = sz2[u * FPST + t];
      const int i0 = 2 * u, i1 = 2 * u + 1;
      {
        float m0 = mdl[i0 * FPST + t];
        float dx = __fsub_rn(c.x, qx);
        float dy = __fsub_rn(c.y, qy);
        float dz = __fsub_rn(zz.x, qz);
        float d  = __fadd_rn(__fadd_rn(__fmul_rn(dx, dx), __fmul_rn(dy, dy)),
                             __fmul_rn(dz, dz));
        float m = fminf(m0, d);
        mdl[i0 * FPST + t] = m;
        bool g = (m > best);
        best = g ? m : best;
        bi   = g ? i0 : bi;
      }
      {
        float m1 = mdl[i1 * FPST + t];
        float dx = __fsub_rn(c.z, qx);
        float dy = __fsub_rn(c.w, qy);
        float dz = __fsub_rn(zz.y, qz);
        float d  = __fadd_rn(__fadd_rn(__fmul_rn(dx, dx), __fmul_rn(dy, dy)),
                             __fmul_rn(dz, dz));
        float m = fminf(m1, d);
        mdl[i1 * FPST + t] = m;
        bool g = (m > best);
        best = g ? m : best;
        bi   = g ? i1 : bi;
      }
    }

    // Streamed strides 6..15, ascending.
#pragma unroll
    for (int u = 0; u < STREAM_STR; ++u) {
      const int i = LDS_STR + u;
      float m0 = mdl[i * FPST + t];
      float dx = __fsub_rn(gx[u], qx);
      float dy = __fsub_rn(gy[u], qy);
      float dz = __fsub_rn(gz[u], qz);
      float d  = __fadd_rn(__fadd_rn(__fmul_rn(dx, dx), __fmul_rn(dy, dy)),
                           __fmul_rn(dz, dz));
      float m = fminf(m0, d);
      mdl[i * FPST + t] = m;
      bool g = (m > best);
      best = g ? m : best;
      bi   = g ? i : bi;
    }

    int bidx = bi * FPST + t;

    // wave argmax reduce, tie -> lower global index (validated)
#pragma unroll
    for (int off = 32; off >= 1; off >>= 1) {
      float ov = __shfl_down(best, off);
      int   oi = __shfl_down(bidx, off);
      if (ov > best || (ov == best && oi < bidx)) { best = ov; bidx = oi; }
    }

    if ((t & 63) == 0) { s_val[p][t >> 6] = best; s_idx[p][t >> 6] = bidx; }
    __syncthreads();

    float bv = s_val[p][0];
    int   bx = s_idx[p][0];
#pragma unroll
    for (int w = 1; w < FPST / 64; ++w) {
      float v = s_val[p][w];
      int   x = s_idx[p][w];
      if (v > bv || (v == bv && x < bx)) { bv = v; bx = x; }
    }

    qx = P[bx * 3 + 0];
    qy = P[bx * 3 + 1];
    qz = P[bx * 3 + 2];

    if (t == 0) {
      slots[b * NPOINT + it] = bx;
      out_ind[b * NPOINT + it] = (float)bx;
      size_t o = (size_t)(b * NPOINT + it) * 3;
      out_q[o + 0] = qx; out_q[o + 1] = qy; out_q[o + 2] = qz;
    }
  }
}

// ===========================================================================
// Dispatch 2: KNN consumers. Blocks 0..511 = knn_mid, 512..1023 = knn_out.
// One wave per query. Bodies unchanged from validated r19.
// ===========================================================================
__global__ __launch_bounds__(KNNT, 4)
void knn_kernel(const float* __restrict__ pts,
                const int* __restrict__ slots,
                float* __restrict__ out_nbr_mid,
                float* __restrict__ out_d_mid,
                float* __restrict__ out_nbr_out,
                float* __restrict__ out_d_out) {
  if (blockIdx.x < 512) {
    // ================= knn_mid role: one wave per query ===================
#pragma clang fp contract(off)
    const int kb   = blockIdx.x;
    const int wid  = kb * 8 + (threadIdx.x >> 6);
    const int lane = threadIdx.x & 63;
    const int b    = wid >> 10;
    const int qi   = wid & (NPOINT - 1);
    const float* C = pts + (size_t)b * NPTS * 3;

    const int widx = slots[b * NPOINT + qi];

    // q coords bit-identical to out_q (fps writes exactly P[widx])
    const float qx = C[widx * 3 + 0];
    const float qy = C[widx * 3 + 1];
    const float qz = C[widx * 3 + 2];
    const float qq = (qx * qx + qy * qy) + qz * qz;

    u64 best[KSEL];
#pragma unroll
    for (int j = 0; j < KSEL; ++j) best[j] = 0xFFFFFFFFFFFFFFFFull;

    for (int j = lane; j < NPTS; j += 64) {
      float px = C[j * 3 + 0], py = C[j * 3 + 1], pz = C[j * 3 + 2];
      float pp  = (px * px + py * py) + pz * pz;
      float dot = __builtin_fmaf(qz, pz, __builtin_fmaf(qy, py, qx * px));
      float d = (qq + pp) - 2.0f * dot;
      d = fmaxf(d, 0.0f);
      u64 key = ((u64)__float_as_uint(d) << 32) | (unsigned)j;
      if (key < best[KSEL - 1]) {
        u64 c = key;
#pragma unroll
        for (int s = 0; s < KSEL; ++s) {
          u64 o = best[s];
          bool l = c < o;
          u64 nb = l ? c : o;
          c = l ? o : c;
          best[s] = nb;
        }
      }
    }

    // LDS-free 64-way merge (validated r14/r16)
    int hp = 1;
    u64 head = best[0];
    int myK = -1, myIdx = 0;
#pragma unroll
    for (int r = 0; r < KSEL; ++r) {
      u64 v = head; int src = lane;
#pragma unroll
      for (int off = 32; off >= 1; off >>= 1) {
        u64 ov = __shfl_down(v, off);
        int os = __shfl_down(src, off);
        if (ov < v) { v = ov; src = os; }  // keys unique (idx embedded)
      }
      v   = __shfl(v, 0);
      src = __shfl(src, 0);
      if (r >= 1 && lane == r - 1) {       // drop r==0 (self)
        myIdx = (int)(unsigned)(v & 0xFFFFFFFFull);
        myK = r - 1;
      }
      if (lane == src) {
        u64 h = 0xFFFFFFFFFFFFFFFFull;
#pragma unroll
        for (int s = 1; s < KSEL; ++s) if (hp == s) h = best[s];
        head = h;
        hp++;
      }
    }

    if (myK >= 0) {
      size_t o = (size_t)(b * NPOINT + qi) * KNN + myK;
      out_nbr_mid[o] = (float)myIdx;
      float sx = C[myIdx * 3 + 0], sy = C[myIdx * 3 + 1],
            sz = C[myIdx * 3 + 2];
      out_d_mid[o * 3 + 0] = qx - sx;
      out_d_mid[o * 3 + 1] = qy - sy;
      out_d_mid[o * 3 + 2] = qz - sz;
    }
  } else {
    // ================= knn_out role: one wave per query ===================
#pragma clang fp contract(off)
    const int kb   = blockIdx.x - 512;
    const int wid  = kb * 8 + (threadIdx.x >> 6);
    const int lane = threadIdx.x & 63;
    const int b    = wid >> 10;
    const int qi   = wid & (NPOINT - 1);
    const float* C = pts + (size_t)b * NPTS * 3;

    // my query's point index
    const int wq = slots[b * NPOINT + qi];
    const float qx = C[wq * 3 + 0];
    const float qy = C[wq * 3 + 1];
    const float qz = C[wq * 3 + 2];
    const float qq = (qx * qx + qy * qy) + qz * qz;

    // candidate point indices for my 16 positions (coalesced slot reads)
    int wj[NPOINT / 64];
#pragma unroll
    for (int u = 0; u < NPOINT / 64; ++u) {
      wj[u] = slots[b * NPOINT + u * 64 + lane];
    }

    u64 best[KSEL];
#pragma unroll
    for (int j = 0; j < KSEL; ++j) best[j] = 0xFFFFFFFFFFFFFFFFull;

#pragma unroll
    for (int u = 0; u < NPOINT / 64; ++u) {
      int j = u * 64 + lane;               // candidate POSITION (the key idx)
      int w = wj[u];
      float px = C[w * 3 + 0], py = C[w * 3 + 1], pz = C[w * 3 + 2];
      float pp  = (px * px + py * py) + pz * pz;
      float dot = __builtin_fmaf(qz, pz, __builtin_fmaf(qy, py, qx * px));
      float d = (qq + pp) - 2.0f * dot;
      d = fmaxf(d, 0.0f);
      u64 key = ((u64)__float_as_uint(d) << 32) | (unsigned)j;
      if (key < best[KSEL - 1]) {
        u64 c = key;
#pragma unroll
        for (int s = 0; s < KSEL; ++s) {
          u64 o = best[s];
          bool l = c < o;
          u64 nb = l ? c : o;
          c = l ? o : c;
          best[s] = nb;
        }
      }
    }

    // LDS-free 64-way merge (validated r14/r16)
    int hp = 1;
    u64 head = best[0];
    int myK = -1, myIdx = 0;
#pragma unroll
    for (int r = 0; r < KSEL; ++r) {
      u64 v = head; int src = lane;
#pragma unroll
      for (int off = 32; off >= 1; off >>= 1) {
        u64 ov = __shfl_down(v, off);
        int os = __shfl_down(src, off);
        if (ov < v) { v = ov; src = os; }
      }
      v   = __shfl(v, 0);
      src = __shfl(src, 0);
      if (r >= 1 && lane == r - 1) {
        myIdx = (int)(unsigned)(v & 0xFFFFFFFFull);
        myK = r - 1;
      }
      if (lane == src) {
        u64 h = 0xFFFFFFFFFFFFFFFFull;
#pragma unroll
        for (int s = 1; s < KSEL; ++s) if (hp == s) h = best[s];
        head = h;
        hp++;
      }
    }

    if (myK >= 0) {
      size_t o = (size_t)(b * NPOINT + qi) * KNN + myK;
      out_nbr_out[o] = (float)myIdx;
      const int w = slots[b * NPOINT + myIdx];
      float sx = C[w * 3 + 0], sy = C[w * 3 + 1], sz = C[w * 3 + 2];
      out_d_out[o * 3 + 0] = qx - sx;
      out_d_out[o * 3 + 1] = qy - sy;
      out_d_out[o * 3 + 2] = qz - sz;
    }
  }
}

// ---------------------------------------------------------------------------
extern "C" void kernel_launch(void* const* d_in, const int* in_sizes, int n_in,
                              void* d_out, int out_size, void* d_ws,
                              size_t ws_size, hipStream_t stream) {
  (void)in_sizes; (void)n_in; (void)out_size; (void)ws_size;
  const float* pts = (const float*)d_in[0];
  float* out = (float*)d_out;

  // ws layout: slots only — 4 x 1024 x 4B = 16 KB (int winner indices)
  int* slots = (int*)d_ws;

  // output layout (floats): [xyz_ind | xyz_query | nbr_mid | d_mid | nbr_out | d_out]
  float* out_nbr_mid = out + (size_t)BATCH * NPOINT * 4;
  float* out_d_mid   = out_nbr_mid + (size_t)BATCH * NPOINT * KNN;
  float* out_nbr_out = out_d_mid + (size_t)BATCH * NPOINT * KNN * 3;
  float* out_d_out   = out_nbr_out + (size_t)BATCH * NPOINT * KNN;

  // Opt in to >64KB dynamic LDS (one-time host-side attribute; validated
  // graph-capture-safe in r23).
  static int lds_set = 0;
  if (!lds_set) {
    (void)hipFuncSetAttribute((const void*)fps_kernel,
                              hipFuncAttributeMaxDynamicSharedMemorySize,
                              DYN_LDS_BYTES);
    lds_set = 1;
  }

  hipLaunchKernelGGL(fps_kernel, dim3(BATCH), dim3(FPST),
                     DYN_LDS_BYTES, stream, pts, out, slots);
  hipLaunchKernelGGL(knn_kernel, dim3(1024), dim3(KNNT), 0, stream,
                     pts, slots, out_nbr_mid, out_d_mid, out_nbr_out,
                     out_d_out);
}

// Round 7
// 3487.403 us; speedup vs baseline: 1.2526x; 1.2526x over previous
//
#include <hip/hip_runtime.h>
#include <stdint.h>

#define BATCH   4
#define NPTS    16384
#define NPOINT  1024
#define KNN     20
#define KSEL    21   // K+1, includes self

typedef unsigned long long u64;

// ---------------------------------------------------------------------------
// r25: UNITS CORRECTION + multi-CU FPS.
// FETCH_SIZE/WRITE_SIZE are KB (hbm_bytes col = x1024) -> total HBM traffic
// was ~0.5MB all session; the r19-r24 "spill to HBM" theory was a 1000x
// units misread. Real profile: ~60% VALU-busy on the 4 active CUs,
// negligible memory traffic -> FPS is a serial per-CU issue/latency chain
// at its single-CU floor (16384 pts x ~12 ops / 128 lanes = 1536 cy +
// reduce/barrier/q-load). The untouched lever: FPS used 4/256 CUs.
// Fix: 4 blocks per batch (4096 pts each, 8 pts/thread in registers -> 32
// persistent VGPRs, fits any observed grant). Per iteration each block
// publishes its (maxdist, idx) candidate to a tagged u64 slot
// (r18-validated protocol: relaxed AGENT atomics, tag [9:0]=it, bit63=0,
// poison 0xAA.. bit63=1 -> invalid, zero tag!=it -> invalid, replay
// deterministic -> idempotent). cand[batch][parity][4] double-buffer
// (256B in ws): a block publishes it+2 only after seeing all it+1
// publishes, each of which sits behind that block's post-poll barrier ->
// no slot overwritten while readable. Key packs tie-break:
// (fbits<<32)|((16383-idx)<<10)|it -> u64 max == max dist, tie -> lowest
// global idx (reference argmax). FP trees / intra-block reduce / scan
// order byte-identical to validated r19.
// knn_kernel unchanged from validated r19.
// ---------------------------------------------------------------------------
#define FPSB   4                         // FPS blocks per batch
#define FPST   512                       // threads per FPS block
#define BLKPTS (NPTS / FPSB)             // 4096 points per block
#define FPPT   (BLKPTS / FPST)           // 8 points per thread
#define KNNT   512

__device__ __forceinline__ float opaque_f(float x) {
  __asm__ volatile("" : "+v"(x));
  return x;
}

#define REPEAT8(M) M(0) M(1) M(2) M(3) M(4) M(5) M(6) M(7)

#define FPS_DECL(i) float px##i, py##i, pz##i, md##i;

#define FPS_INIT(i) { \
    int gidx = blkoff + (i) * FPST + t; \
    px##i = opaque_f(P[gidx * 3 + 0]); \
    py##i = opaque_f(P[gidx * 3 + 1]); \
    pz##i = opaque_f(P[gidx * 3 + 2]); \
    md##i = 1e10f; }

#define FPS_STEP(i) { \
    float dx = __fsub_rn(px##i, qx); \
    float dy = __fsub_rn(py##i, qy); \
    float dz = __fsub_rn(pz##i, qz); \
    float d  = __fadd_rn(__fadd_rn(__fmul_rn(dx, dx), __fmul_rn(dy, dy)), \
                         __fmul_rn(dz, dz)); \
    float m = fminf(md##i, d); \
    md##i = m; \
    bool g = (m > best); \
    best = g ? m : best; \
    bi   = g ? (i) : bi; }

// ===========================================================================
// Dispatch 1: FPS. 16 blocks = 4 batches x 4 sub-blocks. Cross-block winner
// exchange via tagged u64 slots (validated r18 protocol).
// ===========================================================================
__global__ __launch_bounds__(FPST)
void fps_kernel(const float* __restrict__ pts, float* __restrict__ out,
                int* __restrict__ slots, u64* __restrict__ cand) {
  const int gb = blockIdx.x;
  const int b  = gb >> 2;                 // batch
  const int j  = gb & (FPSB - 1);         // sub-block within batch
  const int blkoff = j * BLKPTS;
  const float* P = pts + (size_t)b * NPTS * 3;
  float* out_ind = out;                   // [B,NPOINT] (indices as float)
  float* out_q   = out + BATCH * NPOINT;  // [B,NPOINT,3]
  const int t = threadIdx.x;

  REPEAT8(FPS_DECL)
  REPEAT8(FPS_INIT)

  __shared__ float s_val[2][FPST / 64];
  __shared__ int   s_idx[2][FPST / 64];

  if (j == 0 && t == 0) {
    out_ind[b * NPOINT] = 0.0f;
    slots[b * NPOINT] = 0;
    float ax = P[0], ay = P[1], az = P[2];
    size_t o0 = (size_t)(b * NPOINT) * 3;
    out_q[o0 + 0] = ax; out_q[o0 + 1] = ay; out_q[o0 + 2] = az;
  }
  float qx = P[0], qy = P[1], qz = P[2];

  for (int it = 1; it < NPOINT; ++it) {
    const int p = it & 1;
    float best = -1.0f;
    int bi = 0;
    REPEAT8(FPS_STEP)
    int bidx = blkoff + bi * FPST + t;    // global point index

    // wave argmax reduce, tie -> lower global index (validated r19)
#pragma unroll
    for (int off = 32; off >= 1; off >>= 1) {
      float ov = __shfl_down(best, off);
      int   oi = __shfl_down(bidx, off);
      if (ov > best || (ov == best && oi < bidx)) { best = ov; bidx = oi; }
    }

    if ((t & 63) == 0) { s_val[p][t >> 6] = best; s_idx[p][t >> 6] = bidx; }
    __syncthreads();

    float bv = s_val[p][0];
    int   bx = s_idx[p][0];
#pragma unroll
    for (int w = 1; w < FPST / 64; ++w) {
      float v = s_val[p][w];
      int   x = s_idx[p][w];
      if (v > bv || (v == bv && x < bx)) { bv = v; bx = x; }
    }

    // Publish this block's candidate: [63:32]=dist bits (>=0 -> bit63=0),
    // [23:10]=16383-idx (tie -> lower idx wins u64 max), [9:0]=it tag.
    if (t == 0) {
      u64 pv = ((u64)__float_as_uint(bv) << 32)
             | ((u64)(unsigned)(16383 - bx) << 10)
             | (unsigned)it;
      __hip_atomic_store(&cand[((size_t)b * 2 + p) * FPSB + j], pv,
                         __ATOMIC_RELAXED, __HIP_MEMORY_SCOPE_AGENT);
    }

    // All threads poll the 4 candidates for this (batch, parity, tag).
    u64 wkey = 0;
#pragma unroll
    for (int k = 0; k < FPSB; ++k) {
      const u64* sp = &cand[((size_t)b * 2 + p) * FPSB + k];
      u64 v;
      for (;;) {
        v = __hip_atomic_load(sp, __ATOMIC_RELAXED,
                              __HIP_MEMORY_SCOPE_AGENT);
        if ((v >> 63) == 0 &&
            (unsigned)(v & 0x3FFu) == (unsigned)it) break;
        __builtin_amdgcn_s_sleep(1);
      }
      wkey = (v > wkey) ? v : wkey;
    }
    int wx = 16383 - (int)((wkey >> 10) & 0x3FFFu);

    qx = P[wx * 3 + 0];
    qy = P[wx * 3 + 1];
    qz = P[wx * 3 + 2];

    if (j == 0 && t == 0) {
      slots[b * NPOINT + it] = wx;
      out_ind[b * NPOINT + it] = (float)wx;
      size_t o = (size_t)(b * NPOINT + it) * 3;
      out_q[o + 0] = qx; out_q[o + 1] = qy; out_q[o + 2] = qz;
    }
  }
}

// ===========================================================================
// Dispatch 2: KNN consumers. Blocks 0..511 = knn_mid, 512..1023 = knn_out.
// One wave per query. Bodies unchanged from validated r19.
// ===========================================================================
__global__ __launch_bounds__(KNNT, 4)
void knn_kernel(const float* __restrict__ pts,
                const int* __restrict__ slots,
                float* __restrict__ out_nbr_mid,
                float* __restrict__ out_d_mid,
                float* __restrict__ out_nbr_out,
                float* __restrict__ out_d_out) {
  if (blockIdx.x < 512) {
    // ================= knn_mid role: one wave per query ===================
#pragma clang fp contract(off)
    const int kb   = blockIdx.x;
    const int wid  = kb * 8 + (threadIdx.x >> 6);
    const int lane = threadIdx.x & 63;
    const int b    = wid >> 10;
    const int qi   = wid & (NPOINT - 1);
    const float* C = pts + (size_t)b * NPTS * 3;

    const int widx = slots[b * NPOINT + qi];

    // q coords bit-identical to out_q (fps writes exactly P[widx])
    const float qx = C[widx * 3 + 0];
    const float qy = C[widx * 3 + 1];
    const float qz = C[widx * 3 + 2];
    const float qq = (qx * qx + qy * qy) + qz * qz;

    u64 best[KSEL];
#pragma unroll
    for (int j = 0; j < KSEL; ++j) best[j] = 0xFFFFFFFFFFFFFFFFull;

    for (int j = lane; j < NPTS; j += 64) {
      float px = C[j * 3 + 0], py = C[j * 3 + 1], pz = C[j * 3 + 2];
      float pp  = (px * px + py * py) + pz * pz;
      float dot = __builtin_fmaf(qz, pz, __builtin_fmaf(qy, py, qx * px));
      float d = (qq + pp) - 2.0f * dot;
      d = fmaxf(d, 0.0f);
      u64 key = ((u64)__float_as_uint(d) << 32) | (unsigned)j;
      if (key < best[KSEL - 1]) {
        u64 c = key;
#pragma unroll
        for (int s = 0; s < KSEL; ++s) {
          u64 o = best[s];
          bool l = c < o;
          u64 nb = l ? c : o;
          c = l ? o : c;
          best[s] = nb;
        }
      }
    }

    // LDS-free 64-way merge (validated r14/r16)
    int hp = 1;
    u64 head = best[0];
    int myK = -1, myIdx = 0;
#pragma unroll
    for (int r = 0; r < KSEL; ++r) {
      u64 v = head; int src = lane;
#pragma unroll
      for (int off = 32; off >= 1; off >>= 1) {
        u64 ov = __shfl_down(v, off);
        int os = __shfl_down(src, off);
        if (ov < v) { v = ov; src = os; }  // keys unique (idx embedded)
      }
      v   = __shfl(v, 0);
      src = __shfl(src, 0);
      if (r >= 1 && lane == r - 1) {       // drop r==0 (self)
        myIdx = (int)(unsigned)(v & 0xFFFFFFFFull);
        myK = r - 1;
      }
      if (lane == src) {
        u64 h = 0xFFFFFFFFFFFFFFFFull;
#pragma unroll
        for (int s = 1; s < KSEL; ++s) if (hp == s) h = best[s];
        head = h;
        hp++;
      }
    }

    if (myK >= 0) {
      size_t o = (size_t)(b * NPOINT + qi) * KNN + myK;
      out_nbr_mid[o] = (float)myIdx;
      float sx = C[myIdx * 3 + 0], sy = C[myIdx * 3 + 1],
            sz = C[myIdx * 3 + 2];
      out_d_mid[o * 3 + 0] = qx - sx;
      out_d_mid[o * 3 + 1] = qy - sy;
      out_d_mid[o * 3 + 2] = qz - sz;
    }
  } else {
    // ================= knn_out role: one wave per query ===================
#pragma clang fp contract(off)
    const int kb   = blockIdx.x - 512;
    const int wid  = kb * 8 + (threadIdx.x >> 6);
    const int lane = threadIdx.x & 63;
    const int b    = wid >> 10;
    const int qi   = wid & (NPOINT - 1);
    const float* C = pts + (size_t)b * NPTS * 3;

    // my query's point index
    const int wq = slots[b * NPOINT + qi];
    const float qx = C[wq * 3 + 0];
    const float qy = C[wq * 3 + 1];
    const float qz = C[wq * 3 + 2];
    const float qq = (qx * qx + qy * qy) + qz * qz;

    // candidate point indices for my 16 positions (coalesced slot reads)
    int wj[NPOINT / 64];
#pragma unroll
    for (int u = 0; u < NPOINT / 64; ++u) {
      wj[u] = slots[b * NPOINT + u * 64 + lane];
    }

    u64 best[KSEL];
#pragma unroll
    for (int j = 0; j < KSEL; ++j) best[j] = 0xFFFFFFFFFFFFFFFFull;

#pragma unroll
    for (int u = 0; u < NPOINT / 64; ++u) {
      int j = u * 64 + lane;               // candidate POSITION (the key idx)
      int w = wj[u];
      float px = C[w * 3 + 0], py = C[w * 3 + 1], pz = C[w * 3 + 2];
      float pp  = (px * px + py * py) + pz * pz;
      float dot = __builtin_fmaf(qz, pz, __builtin_fmaf(qy, py, qx * px));
      float d = (qq + pp) - 2.0f * dot;
      d = fmaxf(d, 0.0f);
      u64 key = ((u64)__float_as_uint(d) << 32) | (unsigned)j;
      if (key < best[KSEL - 1]) {
        u64 c = key;
#pragma unroll
        for (int s = 0; s < KSEL; ++s) {
          u64 o = best[s];
          bool l = c < o;
          u64 nb = l ? c : o;
          c = l ? o : c;
          best[s] = nb;
        }
      }
    }

    // LDS-free 64-way merge (validated r14/r16)
    int hp = 1;
    u64 head = best[0];
    int myK = -1, myIdx = 0;
#pragma unroll
    for (int r = 0; r < KSEL; ++r) {
      u64 v = head; int src = lane;
#pragma unroll
      for (int off = 32; off >= 1; off >>= 1) {
        u64 ov = __shfl_down(v, off);
        int os = __shfl_down(src, off);
        if (ov < v) { v = ov; src = os; }
      }
      v   = __shfl(v, 0);
      src = __shfl(src, 0);
      if (r >= 1 && lane == r - 1) {
        myIdx = (int)(unsigned)(v & 0xFFFFFFFFull);
        myK = r - 1;
      }
      if (lane == src) {
        u64 h = 0xFFFFFFFFFFFFFFFFull;
#pragma unroll
        for (int s = 1; s < KSEL; ++s) if (hp == s) h = best[s];
        head = h;
        hp++;
      }
    }

    if (myK >= 0) {
      size_t o = (size_t)(b * NPOINT + qi) * KNN + myK;
      out_nbr_out[o] = (float)myIdx;
      const int w = slots[b * NPOINT + myIdx];
      float sx = C[w * 3 + 0], sy = C[w * 3 + 1], sz = C[w * 3 + 2];
      out_d_out[o * 3 + 0] = qx - sx;
      out_d_out[o * 3 + 1] = qy - sy;
      out_d_out[o * 3 + 2] = qz - sz;
    }
  }
}

// ---------------------------------------------------------------------------
extern "C" void kernel_launch(void* const* d_in, const int* in_sizes, int n_in,
                              void* d_out, int out_size, void* d_ws,
                              size_t ws_size, hipStream_t stream) {
  (void)in_sizes; (void)n_in; (void)out_size; (void)ws_size;
  const float* pts = (const float*)d_in[0];
  float* out = (float*)d_out;

  // ws layout: int slots[4][1024] (16KB) | u64 cand[4][2][4] (256B)
  int* slots = (int*)d_ws;
  u64* cand  = (u64*)((char*)d_ws + BATCH * NPOINT * sizeof(int));

  // output layout (floats): [xyz_ind | xyz_query | nbr_mid | d_mid | nbr_out | d_out]
  float* out_nbr_mid = out + (size_t)BATCH * NPOINT * 4;
  float* out_d_mid   = out_nbr_mid + (size_t)BATCH * NPOINT * KNN;
  float* out_nbr_out = out_d_mid + (size_t)BATCH * NPOINT * KNN * 3;
  float* out_d_out   = out_nbr_out + (size_t)BATCH * NPOINT * KNN;

  hipLaunchKernelGGL(fps_kernel, dim3(BATCH * FPSB), dim3(FPST), 0, stream,
                     pts, out, slots, cand);
  hipLaunchKernelGGL(knn_kernel, dim3(1024), dim3(KNNT), 0, stream,
                     pts, slots, out_nbr_mid, out_d_mid, out_nbr_out,
                     out_d_out);
}